// Round 1
// baseline (431.506 us; speedup 1.0000x reference)
//
#include <hip/hip_runtime.h>
#include <math.h>

#define INC   128
#define OUTC  256
#define NPTS  9
#define BATCH 8
#define HDIM  64
#define WDIM  64
#define HW    4096          // 64*64
#define JLB   36864         // cols per batch = 64*64*9
#define JTOT  294912        // 8 * JLB
#define NTOTF 294912.0f

typedef __bf16 bf16x8 __attribute__((ext_vector_type(8)));
typedef float  f32x4  __attribute__((ext_vector_type(4)));

// ---------------- K0: cw fp32 -> bf16 ----------------
__global__ void k_cvt_cw(const float* __restrict__ cw, __bf16* __restrict__ cwb) {
    int i = blockIdx.x * 256 + threadIdx.x;
    if (i < OUTC * INC) cwb[i] = (__bf16)cw[i];
}

// ---------------- K1: offset conv + sampling prep ----------------
// grid: 9 * 128 blocks of 256 threads. block -> (n, spatial chunk of 256)
__global__ __launch_bounds__(256) void k_prep(
        const float* __restrict__ x, const float* __restrict__ pw,
        const float* __restrict__ pb, int4* __restrict__ sidx,
        float4* __restrict__ sw) {
    int n  = blockIdx.x >> 7;                         // 0..8
    int sp = ((blockIdx.x & 127) << 8) + threadIdx.x; // 0..32767
    int b  = sp >> 12;
    int hh = (sp >> 6) & 63;
    int ww = sp & 63;

    // stage pw channels n and n+9 into LDS: layout [c*9+k][2]
    __shared__ float pwl[INC * 9 * 2];
    for (int i = threadIdx.x; i < INC * 9; i += 256) {
        pwl[i * 2 + 0] = pw[n * (INC * 9) + i];
        pwl[i * 2 + 1] = pw[(n + 9) * (INC * 9) + i];
    }
    __syncthreads();

    const float* xb = x + b * (INC * HW);
    float ax = 0.f, ay = 0.f;
    for (int c = 0; c < INC; ++c) {
        const float* xc = xb + c * HW;
        const float* pc = pwl + c * 18;
        #pragma unroll
        for (int ky = 0; ky < 3; ++ky) {
            int yy = hh - 1 + ky;
            #pragma unroll
            for (int kx = 0; kx < 3; ++kx) {
                int xx = ww - 1 + kx;
                float v = ((unsigned)yy < 64u && (unsigned)xx < 64u)
                            ? xc[yy * 64 + xx] : 0.f;
                int k = ky * 3 + kx;
                ax = fmaf(v, pc[k * 2 + 0], ax);
                ay = fmaf(v, pc[k * 2 + 1], ay);
            }
        }
    }
    ax += pb[n];
    ay += pb[n + 9];

    const float TWO_PI = 6.28318530717958647692f;
    float ang = (float)n * (TWO_PI / 9.0f);
    float px = ax + cosf(ang) + (float)hh;
    float py = ay + sinf(ang) + (float)ww;
    float fx = floorf(px), fy = floorf(py);
    float ltx = fminf(fmaxf(fx,        0.f), 63.f);
    float lty = fminf(fmaxf(fy,        0.f), 63.f);
    float rbx = fminf(fmaxf(fx + 1.f,  0.f), 63.f);
    float rby = fminf(fmaxf(fy + 1.f,  0.f), 63.f);
    float pxc = fminf(fmaxf(px,        0.f), 63.f);
    float pyc = fminf(fmaxf(py,        0.f), 63.f);
    float glt = (1.f + ltx - pxc) * (1.f + lty - pyc);
    float grb = (1.f - rbx + pxc) * (1.f - rby + pyc);
    float glb = (1.f + ltx - pxc) * (1.f - rby + pyc);
    float grt = (1.f - rbx + pxc) * (1.f + lty - pyc);

    int j = b * JLB + (hh * 64 + ww) * 9 + n;
    sidx[j] = make_int4((int)ltx * 64 + (int)lty,
                        (int)rbx * 64 + (int)rby,
                        (int)ltx * 64 + (int)rby,
                        (int)rbx * 64 + (int)lty);
    sw[j] = make_float4(glt, grb, glb, grt);
}

// ---------------- K2: gather-GEMM. WRITE=false: stats pass; true: output pass
// block: 256 threads (4 waves). tile: 256 rows (full OUTC) x 64 cols, K=128.
template <bool WRITE>
__global__ __launch_bounds__(256, 2) void k_gemm(
        const float* __restrict__ x, const __bf16* __restrict__ cwb,
        const int4* __restrict__ sidx, const float4* __restrict__ sw,
        const float* __restrict__ meanb, const float* __restrict__ rstdb,
        const float* __restrict__ gamma, const float* __restrict__ beta,
        float* __restrict__ gstat, float* __restrict__ out) {
    __shared__ uint4 xoffT4[64 * 256 / 16];   // 64 cols x 128 c bf16, swizzled
    __shared__ float snorm[4 * 256];          // mean,rstd,gamma,beta
    __shared__ float ssum[256], ssq[256];
    char* xoffT = (char*)xoffT4;

    int bidx = blockIdx.x;
    int b    = bidx / 576;
    int jl0  = (bidx % 576) * 64;
    int tid  = threadIdx.x;
    int w    = tid >> 6;
    int l    = tid & 63;

    // ---- build xoffT tile: lane = column, wave w covers c in [32w, 32w+32)
    int j0 = b * JLB + jl0;
    int4   qi = sidx[j0 + l];
    float4 qw = sw[j0 + l];
    const float* xb = x + b * (INC * HW);
    #pragma unroll
    for (int c8 = 0; c8 < 4; ++c8) {
        int cbase = w * 32 + c8 * 8;
        bf16x8 pack;
        #pragma unroll
        for (int i = 0; i < 8; ++i) {
            const float* xc = xb + (cbase + i) * HW;
            float v = fmaf(qw.w, xc[qi.w],
                      fmaf(qw.z, xc[qi.z],
                      fmaf(qw.y, xc[qi.y], qw.x * xc[qi.x])));
            pack[i] = (__bf16)v;
        }
        int colbyte = (cbase * 2) ^ ((l & 7) << 4);   // XOR swizzle (G4)
        *(bf16x8*)(xoffT + l * 256 + colbyte) = pack;
    }

    if (WRITE) {
        snorm[tid]       = meanb[tid];
        snorm[256 + tid] = rstdb[tid];
        snorm[512 + tid] = gamma[tid];
        snorm[768 + tid] = beta[tid];
    }

    // ---- A fragments (cw rows for this wave) from global (L2-hot)
    bf16x8 afrag[4][4];   // [mtile][kstep]
    #pragma unroll
    for (int mt = 0; mt < 4; ++mt) {
        int m = w * 64 + mt * 16 + (l & 15);
        #pragma unroll
        for (int ks = 0; ks < 4; ++ks) {
            int k = ks * 32 + (l >> 4) * 8;
            afrag[mt][ks] = *(const bf16x8*)(cwb + m * 128 + k);
        }
    }

    __syncthreads();

    // ---- MFMA main loop
    f32x4 acc[4][4] = {};
    #pragma unroll
    for (int ks = 0; ks < 4; ++ks) {
        bf16x8 bfrag[4];
        #pragma unroll
        for (int nt = 0; nt < 4; ++nt) {
            int row = nt * 16 + (l & 15);
            int colbyte = (ks * 64 + (l >> 4) * 16) ^ ((row & 7) << 4);
            bfrag[nt] = *(const bf16x8*)(xoffT + row * 256 + colbyte);
        }
        #pragma unroll
        for (int mt = 0; mt < 4; ++mt)
            #pragma unroll
            for (int nt = 0; nt < 4; ++nt)
                acc[mt][nt] = __builtin_amdgcn_mfma_f32_16x16x32_bf16(
                    afrag[mt][ks], bfrag[nt], acc[mt][nt], 0, 0, 0);
    }

    if (WRITE) {
        float* outb = out + b * (OUTC * JLB);
        #pragma unroll
        for (int mt = 0; mt < 4; ++mt) {
            #pragma unroll
            for (int r = 0; r < 4; ++r) {
                int o = w * 64 + mt * 16 + (l >> 4) * 4 + r;
                float mean = snorm[o];
                float rstd = snorm[256 + o];
                float gm   = snorm[512 + o];
                float bt   = snorm[768 + o];
                float* orow = outb + o * JLB + jl0 + (l & 15);
                #pragma unroll
                for (int nt = 0; nt < 4; ++nt) {
                    float yv = acc[mt][nt][r];
                    float yn = (yv - mean) * rstd * gm + bt;
                    float so = yn / (1.f + __expf(-yn));
                    orow[nt * 16] = so;
                }
            }
        }
    } else {
        // per-row sum / sumsq over the 64 columns of this block
        #pragma unroll
        for (int mt = 0; mt < 4; ++mt) {
            #pragma unroll
            for (int r = 0; r < 4; ++r) {
                float s = 0.f, q = 0.f;
                #pragma unroll
                for (int nt = 0; nt < 4; ++nt) {
                    float v = acc[mt][nt][r];
                    s += v;
                    q += v * v;
                }
                #pragma unroll
                for (int d = 1; d < 16; d <<= 1) {
                    s += __shfl_xor(s, d, 64);
                    q += __shfl_xor(q, d, 64);
                }
                if ((l & 15) == 0) {
                    int row = w * 64 + mt * 16 + (l >> 4) * 4 + r;
                    ssum[row] = s;
                    ssq[row]  = q;
                }
            }
        }
        __syncthreads();
        float* gs = gstat + (bidx & 63) * 512;   // 64-way replicated
        atomicAdd(gs + tid,       ssum[tid]);
        atomicAdd(gs + 256 + tid, ssq[tid]);
    }
}

// ---------------- K3: reduce replicated stats -> mean, rstd ----------------
__global__ void k_stats(const float* __restrict__ gstat,
                        float* __restrict__ meanb, float* __restrict__ rstdb) {
    int t = threadIdx.x;
    float s = 0.f, q = 0.f;
    for (int r = 0; r < 64; ++r) {
        s += gstat[r * 512 + t];
        q += gstat[r * 512 + 256 + t];
    }
    float mean = s / NTOTF;
    float var  = q / NTOTF - mean * mean;
    meanb[t] = mean;
    rstdb[t] = rsqrtf(var + 1e-5f);
}

// ---------------- host ----------------
extern "C" void kernel_launch(void* const* d_in, const int* in_sizes, int n_in,
                              void* d_out, int out_size, void* d_ws, size_t ws_size,
                              hipStream_t stream) {
    (void)in_sizes; (void)n_in; (void)out_size; (void)ws_size;
    const float* x     = (const float*)d_in[0];
    const float* pw    = (const float*)d_in[1];
    const float* pb    = (const float*)d_in[2];
    const float* cw    = (const float*)d_in[3];
    const float* gamma = (const float*)d_in[4];
    const float* beta  = (const float*)d_in[5];
    float* out = (float*)d_out;

    char* ws = (char*)d_ws;
    int4*   sidx  = (int4*)(ws);                       // 294912*16 = 4,718,592
    float4* swt   = (float4*)(ws + 4718592);           // 4,718,592
    __bf16* cwb   = (__bf16*)(ws + 9437184);           // 65,536
    float*  gstat = (float*)(ws + 9502720);            // 64*512*4 = 131,072
    float*  meanb = (float*)(ws + 9633792);            // 1024
    float*  rstdb = (float*)(ws + 9634816);            // 1024

    hipMemsetAsync(gstat, 0, 64 * 512 * 4, stream);
    k_cvt_cw<<<128, 256, 0, stream>>>(cw, cwb);
    k_prep<<<9 * 128, 256, 0, stream>>>(x, pw, pb, sidx, swt);
    k_gemm<false><<<4608, 256, 0, stream>>>(x, cwb, sidx, swt,
                                            nullptr, nullptr, gamma, beta,
                                            gstat, nullptr);
    k_stats<<<1, 256, 0, stream>>>(gstat, meanb, rstdb);
    k_gemm<true><<<4608, 256, 0, stream>>>(x, cwb, sidx, swt,
                                           meanb, rstdb, gamma, beta,
                                           gstat, out);
}

// Round 2
// 223.622 us; speedup vs baseline: 1.9296x; 1.9296x over previous
//
#include <hip/hip_runtime.h>
#include <math.h>

#define INC   128
#define OUTC  256
#define NPTS  9
#define BATCH 8
#define HDIM  64
#define WDIM  64
#define HW    4096          // 64*64
#define JLB   36864         // cols per batch = 64*64*9
#define JTOT  294912        // 8 * JLB
#define NTOTF 294912.0f

typedef __bf16 bf16x8 __attribute__((ext_vector_type(8)));
typedef float  f32x4  __attribute__((ext_vector_type(4)));

// ---------------- K0: cw fp32 -> bf16 ----------------
__global__ void k_cvt_cw(const float* __restrict__ cw, __bf16* __restrict__ cwb) {
    int i = blockIdx.x * 256 + threadIdx.x;
    if (i < OUTC * INC) cwb[i] = (__bf16)cw[i];
}

// ---------------- K0b: transpose x (b,c,hw) f32 -> xTb (b,hw,c) bf16 -------
// block: 256 threads, tile = 64 hw x 128 c. grid = 8 * 64.
__global__ __launch_bounds__(256) void k_transpose(
        const float* __restrict__ x, __bf16* __restrict__ xTb) {
    __shared__ __bf16 t[64 * 128];          // byte: hw*256 + ((2c)^((hw&15)<<4))
    char* tb = (char*)t;
    int b   = blockIdx.x >> 6;
    int hw0 = (blockIdx.x & 63) << 6;
    int tid = threadIdx.x;
    int lane = tid & 63;
    int cq  = tid >> 6;                     // wave index = channel offset
    const float* xb = x + b * (INC * HW);
    #pragma unroll
    for (int cc = 0; cc < INC; cc += 4) {
        int c = cc + cq;
        float v = xb[c * HW + hw0 + lane];
        *(__bf16*)(tb + lane * 256 + ((2 * c) ^ ((lane & 15) << 4))) = (__bf16)v;
    }
    __syncthreads();
    __bf16* ob = xTb + ((size_t)b * HW + hw0) * INC;
    #pragma unroll
    for (int i = 0; i < 4; ++i) {
        int chunk = i * 256 + tid;
        int hw  = chunk >> 4;
        int c16 = chunk & 15;
        bf16x8 vv = *(bf16x8*)(tb + hw * 256 + ((c16 * 16) ^ ((hw & 15) << 4)));
        *(bf16x8*)(ob + hw * INC + c16 * 8) = vv;
    }
}

// ---------------- K1: offset conv + sampling prep ----------------
__global__ __launch_bounds__(256) void k_prep(
        const float* __restrict__ x, const float* __restrict__ pw,
        const float* __restrict__ pb, int4* __restrict__ sidx,
        float4* __restrict__ sw) {
    int n  = blockIdx.x >> 7;                         // 0..8
    int sp = ((blockIdx.x & 127) << 8) + threadIdx.x; // 0..32767
    int b  = sp >> 12;
    int hh = (sp >> 6) & 63;
    int ww = sp & 63;

    __shared__ float pwl[INC * 9 * 2];
    for (int i = threadIdx.x; i < INC * 9; i += 256) {
        pwl[i * 2 + 0] = pw[n * (INC * 9) + i];
        pwl[i * 2 + 1] = pw[(n + 9) * (INC * 9) + i];
    }
    __syncthreads();

    const float* xb = x + b * (INC * HW);
    float ax = 0.f, ay = 0.f;
    for (int c = 0; c < INC; ++c) {
        const float* xc = xb + c * HW;
        const float* pc = pwl + c * 18;
        #pragma unroll
        for (int ky = 0; ky < 3; ++ky) {
            int yy = hh - 1 + ky;
            #pragma unroll
            for (int kx = 0; kx < 3; ++kx) {
                int xx = ww - 1 + kx;
                float v = ((unsigned)yy < 64u && (unsigned)xx < 64u)
                            ? xc[yy * 64 + xx] : 0.f;
                int k = ky * 3 + kx;
                ax = fmaf(v, pc[k * 2 + 0], ax);
                ay = fmaf(v, pc[k * 2 + 1], ay);
            }
        }
    }
    ax += pb[n];
    ay += pb[n + 9];

    const float TWO_PI = 6.28318530717958647692f;
    float ang = (float)n * (TWO_PI / 9.0f);
    float px = ax + cosf(ang) + (float)hh;
    float py = ay + sinf(ang) + (float)ww;
    float fx = floorf(px), fy = floorf(py);
    float ltx = fminf(fmaxf(fx,        0.f), 63.f);
    float lty = fminf(fmaxf(fy,        0.f), 63.f);
    float rbx = fminf(fmaxf(fx + 1.f,  0.f), 63.f);
    float rby = fminf(fmaxf(fy + 1.f,  0.f), 63.f);
    float pxc = fminf(fmaxf(px,        0.f), 63.f);
    float pyc = fminf(fmaxf(py,        0.f), 63.f);
    float glt = (1.f + ltx - pxc) * (1.f + lty - pyc);
    float grb = (1.f - rbx + pxc) * (1.f - rby + pyc);
    float glb = (1.f + ltx - pxc) * (1.f - rby + pyc);
    float grt = (1.f - rbx + pxc) * (1.f + lty - pyc);

    int j = b * JLB + (hh * 64 + ww) * 9 + n;
    sidx[j] = make_int4((int)ltx * 64 + (int)lty,
                        (int)rbx * 64 + (int)rby,
                        (int)ltx * 64 + (int)rby,
                        (int)rbx * 64 + (int)lty);
    sw[j] = make_float4(glt, grb, glb, grt);
}

// ---------------- K2: gather-GEMM. WRITE=false: stats pass; true: output
// block: 256 threads (4 waves). tile: 256 rows (full OUTC) x 64 cols, K=128.
template <bool WRITE>
__global__ __launch_bounds__(256, 2) void k_gemm(
        const __bf16* __restrict__ xTb, const __bf16* __restrict__ cwb,
        const int4* __restrict__ sidx, const float4* __restrict__ sw,
        const float* __restrict__ scaleb, const float* __restrict__ shiftb,
        float* __restrict__ gstat, float* __restrict__ out) {
    __shared__ uint4 xoffT4[64 * 256 / 16];   // 64 cols x 128 c bf16, swizzled
    __shared__ float saux[512];               // WRITE: scale|shift; else sum|sq
    char* xoffT = (char*)xoffT4;

    int bidx = blockIdx.x;
    int b    = bidx / 576;
    int jl0  = (bidx % 576) * 64;
    int tid  = threadIdx.x;
    int w    = tid >> 6;
    int l    = tid & 63;

    // ---- gather + bilinear interp: thread = (column, channel-quarter)
    int col = tid >> 2;                 // 0..63
    int q   = tid & 3;                  // channels [32q, 32q+32)
    int j   = b * JLB + jl0 + col;
    int4   qi = sidx[j];
    float4 qw = sw[j];
    const __bf16* xtb = xTb + (size_t)b * (HW * INC) + q * 32;

    float accc[32];
    #pragma unroll
    for (int i = 0; i < 32; ++i) accc[i] = 0.f;

    const int   idx4[4] = { qi.x, qi.y, qi.z, qi.w };
    const float wt4[4]  = { qw.x, qw.y, qw.z, qw.w };
    #pragma unroll
    for (int p = 0; p < 4; ++p) {
        const __bf16* rp = xtb + idx4[p] * INC;
        float wp = wt4[p];
        #pragma unroll
        for (int v = 0; v < 4; ++v) {
            bf16x8 vv = *(const bf16x8*)(rp + v * 8);
            #pragma unroll
            for (int i = 0; i < 8; ++i)
                accc[v * 8 + i] = fmaf(wp, (float)vv[i], accc[v * 8 + i]);
        }
    }
    #pragma unroll
    for (int i8 = 0; i8 < 4; ++i8) {
        bf16x8 pk;
        #pragma unroll
        for (int i = 0; i < 8; ++i) pk[i] = (__bf16)accc[i8 * 8 + i];
        int colbyte = (q * 64 + i8 * 16) ^ ((col & 7) << 4);   // XOR swizzle
        *(bf16x8*)(xoffT + col * 256 + colbyte) = pk;
    }

    if (WRITE) {
        saux[tid]       = scaleb[tid];
        saux[256 + tid] = shiftb[tid];
    }

    // ---- A fragments (cw rows for this wave), L2-hot
    bf16x8 afrag[4][4];   // [mtile][kstep]
    #pragma unroll
    for (int mt = 0; mt < 4; ++mt) {
        int m = w * 64 + mt * 16 + (l & 15);
        #pragma unroll
        for (int ks = 0; ks < 4; ++ks) {
            int k = ks * 32 + (l >> 4) * 8;
            afrag[mt][ks] = *(const bf16x8*)(cwb + m * 128 + k);
        }
    }

    __syncthreads();

    // ---- MFMA main loop
    f32x4 acc[4][4] = {};
    #pragma unroll
    for (int ks = 0; ks < 4; ++ks) {
        bf16x8 bfrag[4];
        #pragma unroll
        for (int nt = 0; nt < 4; ++nt) {
            int row = nt * 16 + (l & 15);
            int colbyte = (ks * 64 + (l >> 4) * 16) ^ ((row & 7) << 4);
            bfrag[nt] = *(const bf16x8*)(xoffT + row * 256 + colbyte);
        }
        #pragma unroll
        for (int mt = 0; mt < 4; ++mt)
            #pragma unroll
            for (int nt = 0; nt < 4; ++nt)
                acc[mt][nt] = __builtin_amdgcn_mfma_f32_16x16x32_bf16(
                    afrag[mt][ks], bfrag[nt], acc[mt][nt], 0, 0, 0);
    }

    if (WRITE) {
        float* outb = out + (size_t)b * (OUTC * JLB);
        #pragma unroll
        for (int mt = 0; mt < 4; ++mt) {
            #pragma unroll
            for (int r = 0; r < 4; ++r) {
                int o = w * 64 + mt * 16 + (l >> 4) * 4 + r;
                float sc = saux[o];
                float sh = saux[256 + o];
                float* orow = outb + (size_t)o * JLB + jl0 + (l & 15);
                #pragma unroll
                for (int nt = 0; nt < 4; ++nt) {
                    float yn = fmaf(acc[mt][nt][r], sc, sh);
                    float so = yn / (1.f + __expf(-yn));
                    orow[nt * 16] = so;
                }
            }
        }
    } else {
        float* ssum = saux;
        float* ssq  = saux + 256;
        #pragma unroll
        for (int mt = 0; mt < 4; ++mt) {
            #pragma unroll
            for (int r = 0; r < 4; ++r) {
                float s = 0.f, qq = 0.f;
                #pragma unroll
                for (int nt = 0; nt < 4; ++nt) {
                    float v = acc[mt][nt][r];
                    s += v;
                    qq += v * v;
                }
                #pragma unroll
                for (int d = 1; d < 16; d <<= 1) {
                    s  += __shfl_xor(s, d, 64);
                    qq += __shfl_xor(qq, d, 64);
                }
                if ((l & 15) == 0) {
                    int row = w * 64 + mt * 16 + (l >> 4) * 4 + r;
                    ssum[row] = s;
                    ssq[row]  = qq;
                }
            }
        }
        __syncthreads();
        float* gs = gstat + (bidx & 63) * 512;   // 64-way replicated
        atomicAdd(gs + tid,       ssum[tid]);
        atomicAdd(gs + 256 + tid, ssq[tid]);
    }
}

// ---------------- K3: reduce stats -> scale, shift ----------------
__global__ void k_stats(const float* __restrict__ gstat,
                        const float* __restrict__ gamma,
                        const float* __restrict__ beta,
                        float* __restrict__ scaleb, float* __restrict__ shiftb) {
    int t = threadIdx.x;
    float s = 0.f, q = 0.f;
    for (int r = 0; r < 64; ++r) {
        s += gstat[r * 512 + t];
        q += gstat[r * 512 + 256 + t];
    }
    float mean = s / NTOTF;
    float var  = q / NTOTF - mean * mean;
    float rstd = rsqrtf(var + 1e-5f);
    float sc = rstd * gamma[t];
    scaleb[t] = sc;
    shiftb[t] = beta[t] - mean * sc;
}

// ---------------- host ----------------
extern "C" void kernel_launch(void* const* d_in, const int* in_sizes, int n_in,
                              void* d_out, int out_size, void* d_ws, size_t ws_size,
                              hipStream_t stream) {
    (void)in_sizes; (void)n_in; (void)out_size; (void)ws_size;
    const float* x     = (const float*)d_in[0];
    const float* pw    = (const float*)d_in[1];
    const float* pb    = (const float*)d_in[2];
    const float* cw    = (const float*)d_in[3];
    const float* gamma = (const float*)d_in[4];
    const float* beta  = (const float*)d_in[5];
    float* out = (float*)d_out;

    char* ws = (char*)d_ws;
    __bf16* xTb   = (__bf16*)(ws);                     // 8,388,608
    int4*   sidx  = (int4*)(ws + 8388608);             // 4,718,592
    float4* swt   = (float4*)(ws + 13107200);          // 4,718,592
    __bf16* cwb   = (__bf16*)(ws + 17825792);          // 65,536
    float*  gstat = (float*)(ws + 17891328);           // 131,072
    float*  scaleb= (float*)(ws + 18022400);           // 1,024
    float*  shiftb= (float*)(ws + 18023424);           // 1,024

    hipMemsetAsync(gstat, 0, 64 * 512 * 4, stream);
    k_cvt_cw<<<128, 256, 0, stream>>>(cw, cwb);
    k_transpose<<<512, 256, 0, stream>>>(x, xTb);
    k_prep<<<9 * 128, 256, 0, stream>>>(x, pw, pb, sidx, swt);
    k_gemm<false><<<4608, 256, 0, stream>>>(xTb, cwb, sidx, swt,
                                            nullptr, nullptr, gstat, nullptr);
    k_stats<<<1, 256, 0, stream>>>(gstat, gamma, beta, scaleb, shiftb);
    k_gemm<true><<<4608, 256, 0, stream>>>(xTb, cwb, sidx, swt,
                                           scaleb, shiftb, gstat, out);
}